// Round 7
// baseline (486.192 us; speedup 1.0000x reference)
//
#include <hip/hip_runtime.h>

// Graphormer encoder — bf16 MFMA GEMMs (m97-style 128x128 tile + global_load_lds),
// fp32 residual path. Attention is block-diagonal (64 graphs x 32 nodes).
// Last layer computes only what reaches the output (virtual rows).

#define NG   64
#define NP   31
#define NORI 1984
#define NT   2048
#define DIM  512
#define NHD  8
#define DKH  64
#define FFD  2048
#define NLAY 4
#define NFEA 32

typedef __attribute__((ext_vector_type(8))) short short8;
typedef __attribute__((ext_vector_type(4))) float floatx4;

typedef __attribute__((address_space(3))) unsigned int lds_u32;
typedef const __attribute__((address_space(1))) unsigned int glb_u32;

__device__ __forceinline__ void gload16(const unsigned short* g, unsigned short* l) {
    // async global->LDS, 16B per lane; LDS dest = wave-uniform base + lane*16
    __builtin_amdgcn_global_load_lds((glb_u32*)g, (lds_u32*)l, 16, 0, 0);
}

__device__ __forceinline__ unsigned short f2bf(float f) {
    union { float f; unsigned u; } v; v.f = f;
    unsigned r = v.u + 0x7fffu + ((v.u >> 16) & 1u);
    return (unsigned short)(r >> 16);
}
__device__ __forceinline__ float bf2f(unsigned short u) {
    union { unsigned u; float f; } v; v.u = ((unsigned)u) << 16;
    return v.f;
}

// ---------------------------------------------------------------- build B blocks
__global__ __launch_bounds__(256) void build_B(
    const int* __restrict__ sp, const float* __restrict__ db,
    const float* __restrict__ virt_bias, float* __restrict__ Bg)
{
    int g = blockIdx.x;
    float vb = virt_bias[0];
    for (int e = threadIdx.x; e < 1024; e += 256) {
        int i = e >> 5, j = e & 31;
        float v;
        if (i == j) v = db[0];
        else if (i < NP && j < NP) {
            int s = sp[(size_t)(g * NP + i) * NORI + g * NP + j];
            v = db[s < 100 ? s : 100];
        } else v = vb;
        Bg[(size_t)g * 1024 + e] = v;
    }
}

// ---------------------------------------------------------------- init h (fp32)
__global__ __launch_bounds__(256) void init_h(
    const float* __restrict__ x, const int* __restrict__ degrees,
    const float* __restrict__ init_W, const float* __restrict__ init_b,
    const float* __restrict__ cent_emb, float* __restrict__ h)
{
    int n = blockIdx.x;
    int tid = threadIdx.x;
    __shared__ float xs[NFEA];
    if (n < NORI && tid < NFEA) xs[tid] = x[(size_t)n * NFEA + tid];
    __syncthreads();
    int deg = degrees[n]; if (deg > 100) deg = 100;
    for (int d = tid; d < DIM; d += 256) {
        float v = cent_emb[(size_t)deg * DIM + d];
        if (n < NORI) {
            float acc = init_b[d];
            #pragma unroll
            for (int k = 0; k < NFEA; ++k) acc += xs[k] * init_W[(size_t)k * DIM + d];
            v += acc;
        }
        h[(size_t)n * DIM + d] = v;
    }
}

// ---------------------------------------------------------------- weight prep
__global__ __launch_bounds__(256) void qkv_prep(
    const float* __restrict__ Wq, const float* __restrict__ Wk, const float* __restrict__ Wv,
    unsigned short* __restrict__ Wt)
{
    int tile = blockIdx.x;          // 96 slices * 32 tiles
    int slice = tile >> 5;
    int tloc = tile & 31;
    int dt = tloc >> 1, kt = tloc & 1;
    int l = slice / 24; int rem = slice % 24; int which = rem >> 3; int hh = rem & 7;
    const float* W = (which == 0) ? Wq : (which == 1) ? Wk : Wv;
    const float* in = W + (size_t)(l * 8 + hh) * DIM * DKH;
    __shared__ float tl[32][33];
    int tr = threadIdx.x >> 5, tc = threadIdx.x & 31;
    #pragma unroll
    for (int p = 0; p < 4; ++p)
        tl[tr + p * 8][tc] = in[(size_t)(dt * 32 + tr + p * 8) * DKH + kt * 32 + tc];
    __syncthreads();
    unsigned short* out = Wt + ((size_t)l * 1536 + which * 512 + hh * 64 + kt * 32) * DIM + dt * 32;
    #pragma unroll
    for (int p = 0; p < 4; ++p)
        out[(size_t)(tr + p * 8) * DIM + tc] = f2bf(tl[tc][tr + p * 8]);
}

__global__ __launch_bounds__(256) void bias_prep(
    const float* __restrict__ bq, const float* __restrict__ bk, const float* __restrict__ bv,
    float* __restrict__ bqkv)
{
    int idx = blockIdx.x * 256 + threadIdx.x;
    if (idx >= NLAY * 1536) return;
    int l = idx / 1536, c = idx % 1536;
    int which = c >> 9, cc = c & 511;
    const float* b = (which == 0) ? bq : (which == 1) ? bk : bv;
    bqkv[idx] = b[(size_t)l * 512 + cc];
}

// combined transpose of Wo/W1/W2 -> [C][R] bf16, one launch.
__global__ __launch_bounds__(256) void prep_w(
    const float* __restrict__ Wo, const float* __restrict__ W1, const float* __restrict__ W2,
    unsigned short* __restrict__ Wo_t, unsigned short* __restrict__ W1_t,
    unsigned short* __restrict__ W2_t)
{
    int id = blockIdx.x;
    const float* in; unsigned short* out; int R, C, l, rt, ct;
    if (id < 1024) {
        l = id >> 8; int t = id & 255; rt = t >> 4; ct = t & 15;
        in = Wo; out = Wo_t; R = 512; C = 512;
    } else if (id < 5120) {
        int t2 = id - 1024; l = t2 >> 10; int t = t2 & 1023; rt = t >> 6; ct = t & 63;
        in = W1; out = W1_t; R = 512; C = 2048;
    } else {
        int t2 = id - 5120; l = t2 >> 10; int t = t2 & 1023; rt = t >> 4; ct = t & 15;
        in = W2; out = W2_t; R = 2048; C = 512;
    }
    const float* ip = in + (size_t)l * R * C;
    unsigned short* op = out + (size_t)l * R * C;
    int r0 = rt * 32, c0 = ct * 32;
    __shared__ float tl[32][33];
    int tr = threadIdx.x >> 5, tc = threadIdx.x & 31;
    #pragma unroll
    for (int p = 0; p < 4; ++p)
        tl[tr + p * 8][tc] = ip[(size_t)(r0 + tr + p * 8) * C + c0 + tc];
    __syncthreads();
    #pragma unroll
    for (int p = 0; p < 4; ++p)
        op[(size_t)(c0 + tr + p * 8) * R + r0 + tc] = f2bf(tl[tc][tr + p * 8]);
}

// ---------------------------------------------------------------- layernorm: fp32 in -> bf16 out
__global__ __launch_bounds__(256) void layernorm_bf16(
    const float* __restrict__ in, unsigned short* __restrict__ out, int row0)
{
    int n = row0 + blockIdx.x;
    int tid = threadIdx.x;
    const float* row = in + (size_t)n * DIM;
    float v0 = row[tid], v1 = row[tid + 256];
    float s = v0 + v1;
    float sq = v0 * v0 + v1 * v1;
    #pragma unroll
    for (int off = 32; off > 0; off >>= 1) {
        s  += __shfl_down(s, off);
        sq += __shfl_down(sq, off);
    }
    __shared__ float red[8];
    int wave = tid >> 6;
    if ((tid & 63) == 0) { red[wave] = s; red[4 + wave] = sq; }
    __syncthreads();
    float ts  = red[0] + red[1] + red[2] + red[3];
    float tsq = red[4] + red[5] + red[6] + red[7];
    float m   = ts * (1.0f / DIM);
    float var = tsq * (1.0f / DIM) - m * m;
    float inv = rsqrtf(var + 1e-5f);
    out[(size_t)n * DIM + tid]       = f2bf((v0 - m) * inv);
    out[(size_t)n * DIM + tid + 256] = f2bf((v1 - m) * inv);
}

// ---------------------------------------------------------------- 128x128 MFMA GEMM (m97-style)
// C = A@Bt^T. 256 thr, 4 waves each 64x64 (4x4 frags 16x16x32). BK=64.
// Unpadded LDS [128][64]; staging via global_load_lds width-16.
// SPLITK==1: out = +bias (+relu), fp32/bf16. SPLITK>1: atomicAdd into fp32 out
// (already holds residual); bz==0 adds bias.
// flags: 1=relu, 2=bf16 out, 4=last-QKV (skip Q cols for fully-non-virt row blocks)
template<int SPLITK>
__global__ __launch_bounds__(256) void gemm128(
    const unsigned short* __restrict__ A, const unsigned short* __restrict__ Bt,
    const float* __restrict__ bias, void* __restrict__ out,
    int Nfull, int K, int moff, int flags)
{
    __shared__ __align__(16) unsigned short Asl[128 * 64];
    __shared__ __align__(16) unsigned short Bsl[128 * 64];
    int tid = threadIdx.x;
    int row0 = moff + blockIdx.y * 128, col0 = blockIdx.x * 128;
    if ((flags & 4) && col0 < 512 && row0 + 128 <= NORI) return;
    int kslice = K / SPLITK;
    int kbeg = blockIdx.z * kslice;
    int wave = tid >> 6, lane = tid & 63;
    int quad = lane >> 4, m16 = lane & 15;
    int mw = (wave >> 1) * 64, nw = (wave & 1) * 64;
    int lrow = lane >> 3;             // 0..7
    int lcol = (lane & 7) * 8;        // element offset within K-tile
    floatx4 acc[4][4] = {};
    for (int k0 = kbeg; k0 < kbeg + kslice; k0 += 64) {
        #pragma unroll
        for (int i = 0; i < 4; ++i) {
            int seg = wave * 4 + i;               // 16 segments of 8 rows
            int r = seg * 8 + lrow;
            gload16(A  + (size_t)(row0 + r) * K + k0 + lcol, Asl + seg * 512);
            gload16(Bt + (size_t)(col0 + r) * K + k0 + lcol, Bsl + seg * 512);
        }
        __syncthreads();
        #pragma unroll
        for (int ks = 0; ks < 64; ks += 32) {
            short8 a[4], b[4];
            #pragma unroll
            for (int mi = 0; mi < 4; ++mi)
                a[mi] = *(const short8*)(Asl + (mw + mi * 16 + m16) * 64 + ks + quad * 8);
            #pragma unroll
            for (int ni = 0; ni < 4; ++ni)
                b[ni] = *(const short8*)(Bsl + (nw + ni * 16 + m16) * 64 + ks + quad * 8);
            #pragma unroll
            for (int mi = 0; mi < 4; ++mi)
                #pragma unroll
                for (int ni = 0; ni < 4; ++ni)
                    acc[mi][ni] = __builtin_amdgcn_mfma_f32_16x16x32_bf16(
                        a[mi], b[ni], acc[mi][ni], 0, 0, 0);
        }
        __syncthreads();
    }
    if (SPLITK == 1) {
        int do_relu = flags & 1, out_bf = flags & 2;
        #pragma unroll
        for (int mi = 0; mi < 4; ++mi) {
            #pragma unroll
            for (int ni = 0; ni < 4; ++ni) {
                int col = col0 + nw + ni * 16 + m16;
                float bval = bias[col];
                #pragma unroll
                for (int rr = 0; rr < 4; ++rr) {
                    int row = row0 + mw + mi * 16 + quad * 4 + rr;
                    float v = acc[mi][ni][rr] + bval;
                    if (do_relu) v = fmaxf(v, 0.0f);
                    if (out_bf) ((unsigned short*)out)[(size_t)row * Nfull + col] = f2bf(v);
                    else        ((float*)out)[(size_t)row * Nfull + col] = v;
                }
            }
        }
    } else {
        float* o = (float*)out;
        float bscale = (blockIdx.z == 0) ? 1.0f : 0.0f;
        #pragma unroll
        for (int mi = 0; mi < 4; ++mi) {
            #pragma unroll
            for (int ni = 0; ni < 4; ++ni) {
                int col = col0 + nw + ni * 16 + m16;
                float bval = bias[col] * bscale;
                #pragma unroll
                for (int rr = 0; rr < 4; ++rr) {
                    int row = row0 + mw + mi * 16 + quad * 4 + rr;
                    atomicAdd(&o[(size_t)row * Nfull + col], acc[mi][ni][rr] + bval);
                }
            }
        }
    }
}

// ---------------------------------------------------------------- 64x64 MFMA GEMM (small M)
// Used for last-layer M=64 pieces. Same semantics as before.
template<int SPLITK>
__global__ __launch_bounds__(256) void gemm64(
    const unsigned short* __restrict__ A, const unsigned short* __restrict__ Bt,
    const float* __restrict__ bias, void* __restrict__ out,
    int Nfull, int K, int moff, int flags)
{
    __shared__ __align__(16) unsigned short Asl[64 * 72];
    __shared__ __align__(16) unsigned short Bsl[64 * 72];
    int tid = threadIdx.x;
    int row0 = moff + blockIdx.y * 64, col0 = blockIdx.x * 64;
    int kslice = K / SPLITK;
    int kbeg = blockIdx.z * kslice;
    int wave = tid >> 6, lane = tid & 63;
    int quad = lane >> 4, m16 = lane & 15;
    int mw = (wave >> 1) * 32, nw = (wave & 1) * 32;
    floatx4 acc[2][2] = {};
    for (int k0 = kbeg; k0 < kbeg + kslice; k0 += 64) {
        #pragma unroll
        for (int p = 0; p < 2; ++p) {
            int idx = (p * 256 + tid) * 8;
            int r = idx >> 6, kk = idx & 63;
            *(float4*)(Asl + r * 72 + kk) =
                *(const float4*)(A + (size_t)(row0 + r) * K + k0 + kk);
            *(float4*)(Bsl + r * 72 + kk) =
                *(const float4*)(Bt + (size_t)(col0 + r) * K + k0 + kk);
        }
        __syncthreads();
        #pragma unroll
        for (int ks = 0; ks < 64; ks += 32) {
            short8 a[2], b[2];
            #pragma unroll
            for (int mi = 0; mi < 2; ++mi)
                a[mi] = *(const short8*)(Asl + (mw + mi * 16 + m16) * 72 + ks + quad * 8);
            #pragma unroll
            for (int ni = 0; ni < 2; ++ni)
                b[ni] = *(const short8*)(Bsl + (nw + ni * 16 + m16) * 72 + ks + quad * 8);
            #pragma unroll
            for (int mi = 0; mi < 2; ++mi)
                #pragma unroll
                for (int ni = 0; ni < 2; ++ni)
                    acc[mi][ni] = __builtin_amdgcn_mfma_f32_16x16x32_bf16(
                        a[mi], b[ni], acc[mi][ni], 0, 0, 0);
        }
        __syncthreads();
    }
    if (SPLITK == 1) {
        int do_relu = flags & 1, out_bf = flags & 2;
        #pragma unroll
        for (int mi = 0; mi < 2; ++mi) {
            #pragma unroll
            for (int ni = 0; ni < 2; ++ni) {
                int col = col0 + nw + ni * 16 + m16;
                float bval = bias[col];
                #pragma unroll
                for (int rr = 0; rr < 4; ++rr) {
                    int row = row0 + mw + mi * 16 + quad * 4 + rr;
                    float v = acc[mi][ni][rr] + bval;
                    if (do_relu) v = fmaxf(v, 0.0f);
                    if (out_bf) ((unsigned short*)out)[(size_t)row * Nfull + col] = f2bf(v);
                    else        ((float*)out)[(size_t)row * Nfull + col] = v;
                }
            }
        }
    } else {
        float* o = (float*)out;
        float bscale = (blockIdx.z == 0) ? 1.0f : 0.0f;
        #pragma unroll
        for (int mi = 0; mi < 2; ++mi) {
            #pragma unroll
            for (int ni = 0; ni < 2; ++ni) {
                int col = col0 + nw + ni * 16 + m16;
                float bval = bias[col] * bscale;
                #pragma unroll
                for (int rr = 0; rr < 4; ++rr) {
                    int row = row0 + mw + mi * 16 + quad * 4 + rr;
                    atomicAdd(&o[(size_t)row * Nfull + col], acc[mi][ni][rr] + bval);
                }
            }
        }
    }
}

// ---------------------------------------------------------------- block attention (layers 0..2)
__global__ __launch_bounds__(256) void attention(
    const unsigned short* __restrict__ qkv,  // [NT][1536] bf16, Q|K|V head-major
    const float* __restrict__ Bg,            // [NG][32][32]
    unsigned short* __restrict__ O)          // [NT][512] bf16 head-major
{
    int g = blockIdx.x >> 3;
    int hh = blockIdx.x & 7;
    __shared__ float Qs[32][65], Ks[32][65], Vs[32][65];
    __shared__ float S[32][33];
    int tid = threadIdx.x;
    int i = tid >> 3;
    int c0 = (tid & 7) * 8;
    int gn = (i < NP) ? g * NP + i : NORI + g;
    const unsigned short* base = qkv + (size_t)gn * 1536 + hh * DKH;
    short8 qv = *(const short8*)(base + c0);
    short8 kv = *(const short8*)(base + 512 + c0);
    short8 vv = *(const short8*)(base + 1024 + c0);
    #pragma unroll
    for (int j = 0; j < 8; ++j) {
        Qs[i][c0 + j] = bf2f((unsigned short)qv[j]);
        Ks[i][c0 + j] = bf2f((unsigned short)kv[j]);
        Vs[i][c0 + j] = bf2f((unsigned short)vv[j]);
    }
    __syncthreads();
    const float scale = 0.125f;
    #pragma unroll
    for (int e = 0; e < 4; ++e) {
        int idx = tid + e * 256;
        int si = idx >> 5, sj = idx & 31;
        float dot = 0.0f;
        #pragma unroll
        for (int k = 0; k < DKH; ++k) dot += Qs[si][k] * Ks[sj][k];
        S[si][sj] = dot * scale + Bg[(size_t)g * 1024 + si * 32 + sj];
    }
    __syncthreads();
    if (tid < 32) {
        float mx = -1e30f;
        #pragma unroll
        for (int j = 0; j < 32; ++j) mx = fmaxf(mx, S[tid][j]);
        float sum = 0.0f;
        #pragma unroll
        for (int j = 0; j < 32; ++j) { float e = __expf(S[tid][j] - mx); S[tid][j] = e; sum += e; }
        float inv = 1.0f / sum;
        #pragma unroll
        for (int j = 0; j < 32; ++j) S[tid][j] *= inv;
    }
    __syncthreads();
    short8 ov;
    #pragma unroll
    for (int cc = 0; cc < 8; ++cc) {
        float acc = 0.0f;
        #pragma unroll
        for (int j = 0; j < 32; ++j) acc += S[i][j] * Vs[j][c0 + cc];
        ov[cc] = (short)f2bf(acc);
    }
    *(short8*)(O + (size_t)gn * DIM + hh * DKH + c0) = ov;
}

// ---------------------------------------------------------------- last-layer attention
__global__ __launch_bounds__(64) void attention_last(
    const unsigned short* __restrict__ qkv, const float* __restrict__ Bg,
    unsigned short* __restrict__ O)
{
    int g = blockIdx.x >> 3, hh = blockIdx.x & 7;
    __shared__ float Ks[32][65], Vs[32][65];
    __shared__ float Qs[64], P[32];
    int tid = threadIdx.x;
    int j = tid & 31, hf = tid >> 5;
    int gn = (j < NP) ? g * NP + j : NORI + g;
    const unsigned short* kb = qkv + (size_t)gn * 1536 + hh * DKH + 512 + hf * 32;
    #pragma unroll
    for (int c = 0; c < 32; c += 8) {
        short8 k8 = *(const short8*)(kb + c);
        short8 v8 = *(const short8*)(kb + 512 + c);
        #pragma unroll
        for (int t = 0; t < 8; ++t) {
            Ks[j][hf * 32 + c + t] = bf2f((unsigned short)k8[t]);
            Vs[j][hf * 32 + c + t] = bf2f((unsigned short)v8[t]);
        }
    }
    Qs[tid] = bf2f(qkv[(size_t)(NORI + g) * 1536 + hh * DKH + tid]);
    __syncthreads();
    float s;
    if (tid < 32) {
        float dot = 0.0f;
        #pragma unroll
        for (int k = 0; k < 64; ++k) dot += Qs[k] * Ks[tid][k];
        s = dot * 0.125f + Bg[(size_t)g * 1024 + 31 * 32 + tid];
    } else s = -1e30f;
    float mx = s;
    #pragma unroll
    for (int off = 32; off > 0; off >>= 1) mx = fmaxf(mx, __shfl_xor(mx, off));
    float e = (tid < 32) ? __expf(s - mx) : 0.0f;
    float sum = e;
    #pragma unroll
    for (int off = 32; off > 0; off >>= 1) sum += __shfl_xor(sum, off);
    if (tid < 32) P[tid] = e / sum;
    __syncthreads();
    float acc = 0.0f;
    #pragma unroll
    for (int jj = 0; jj < 32; ++jj) acc += P[jj] * Vs[jj][tid];
    O[(size_t)(NORI + g) * DIM + hh * DKH + tid] = f2bf(acc);
}

// ---------------------------------------------------------------- launch
extern "C" void kernel_launch(void* const* d_in, const int* in_sizes, int n_in,
                              void* d_out, int out_size, void* d_ws, size_t ws_size,
                              hipStream_t stream)
{
    const float* x        = (const float*)d_in[0];
    const int*   sp       = (const int*)d_in[1];
    const int*   degrees  = (const int*)d_in[3];
    const float* init_W   = (const float*)d_in[4];
    const float* init_b   = (const float*)d_in[5];
    const float* cent_emb = (const float*)d_in[6];
    const float* db       = (const float*)d_in[7];
    const float* vbias    = (const float*)d_in[8];
    const float* Wq       = (const float*)d_in[9];
    const float* bq       = (const float*)d_in[10];
    const float* Wk       = (const float*)d_in[11];
    const float* bk       = (const float*)d_in[12];
    const float* Wv       = (const float*)d_in[13];
    const float* bv       = (const float*)d_in[14];
    const float* Wo       = (const float*)d_in[15];
    const float* bo       = (const float*)d_in[16];
    const float* W1       = (const float*)d_in[17];
    const float* b1       = (const float*)d_in[18];
    const float* W2       = (const float*)d_in[19];
    const float* b2       = (const float*)d_in[20];

    char* ws = (char*)d_ws;
    float*          h      = (float*)ws;          ws += (size_t)NT * DIM * 4;
    unsigned short* hn     = (unsigned short*)ws; ws += (size_t)NT * DIM * 2;
    unsigned short* o      = (unsigned short*)ws; ws += (size_t)NT * DIM * 2;
    unsigned short* qkv    = (unsigned short*)ws; ws += (size_t)NT * FFD * 2;      // aliased qkv/ffn
    float*          Bg     = (float*)ws;          ws += (size_t)NG * 1024 * 4;
    unsigned short* Wqkv_t = (unsigned short*)ws; ws += (size_t)NLAY * 1536 * DIM * 2;
    unsigned short* Wo_t   = (unsigned short*)ws; ws += (size_t)NLAY * DIM * DIM * 2;
    unsigned short* W1_t   = (unsigned short*)ws; ws += (size_t)NLAY * FFD * DIM * 2;
    unsigned short* W2_t   = (unsigned short*)ws; ws += (size_t)NLAY * DIM * FFD * 2;
    float*          bqkv   = (float*)ws;          ws += (size_t)NLAY * 1536 * 4;
    unsigned short* ffnb   = qkv;

    // prep
    build_B<<<NG, 256, 0, stream>>>(sp, db, vbias, Bg);
    init_h<<<NT, 256, 0, stream>>>(x, degrees, init_W, init_b, cent_emb, h);
    qkv_prep<<<96 * 32, 256, 0, stream>>>(Wq, Wk, Wv, Wqkv_t);
    bias_prep<<<(NLAY * 1536 + 255) / 256, 256, 0, stream>>>(bq, bk, bv, bqkv);
    prep_w<<<9216, 256, 0, stream>>>(Wo, W1, W2, Wo_t, W1_t, W2_t);

    for (int l = 0; l < NLAY - 1; ++l) {
        layernorm_bf16<<<NT, 256, 0, stream>>>(h, hn, 0);
        gemm128<1><<<dim3(1536 / 128, NT / 128), 256, 0, stream>>>(
            hn, Wqkv_t + (size_t)l * 1536 * DIM, bqkv + (size_t)l * 1536,
            qkv, 1536, DIM, 0, /*bf16 out*/2);
        attention<<<NG * NHD, 256, 0, stream>>>(qkv, Bg, o);
        gemm128<4><<<dim3(DIM / 128, NT / 128, 4), 256, 0, stream>>>(
            o, Wo_t + (size_t)l * DIM * DIM, bo + (size_t)l * DIM,
            h, DIM, DIM, 0, 0);
        layernorm_bf16<<<NT, 256, 0, stream>>>(h, hn, 0);
        gemm128<1><<<dim3(FFD / 128, NT / 128), 256, 0, stream>>>(
            hn, W1_t + (size_t)l * FFD * DIM, b1 + (size_t)l * FFD,
            ffnb, FFD, DIM, 0, /*relu+bf16*/3);
        gemm128<4><<<dim3(DIM / 128, NT / 128, 4), 256, 0, stream>>>(
            ffnb, W2_t + (size_t)l * DIM * FFD, b2 + (size_t)l * DIM,
            h, DIM, FFD, 0, 0);
    }

    // ---- last layer: only virtual rows reach the output ----
    {
        int l = NLAY - 1;
        layernorm_bf16<<<NT, 256, 0, stream>>>(h, hn, 0);
        // K,V for all rows; Q only for row blocks containing virtual rows
        gemm128<1><<<dim3(1536 / 128, NT / 128), 256, 0, stream>>>(
            hn, Wqkv_t + (size_t)l * 1536 * DIM, bqkv + (size_t)l * 1536,
            qkv, 1536, DIM, 0, /*bf16 out + lastQKV*/6);
        attention_last<<<NG * NHD, 64, 0, stream>>>(qkv, Bg, o);
        gemm64<8><<<dim3(DIM / 64, 1, 8), 256, 0, stream>>>(
            o, Wo_t + (size_t)l * DIM * DIM, bo + (size_t)l * DIM,
            h, DIM, DIM, NORI, 0);
        layernorm_bf16<<<NG, 256, 0, stream>>>(h, hn, NORI);
        gemm64<1><<<dim3(FFD / 64, 1), 256, 0, stream>>>(
            hn, W1_t + (size_t)l * FFD * DIM, b1 + (size_t)l * FFD,
            ffnb, FFD, DIM, NORI, 3);
        gemm64<8><<<dim3(DIM / 64, 1, 8), 256, 0, stream>>>(
            ffnb, W2_t + (size_t)l * DIM * FFD, b2 + (size_t)l * DIM,
            h, DIM, FFD, NORI, 0);
    }

    hipMemcpyAsync(d_out, h + (size_t)NORI * DIM, (size_t)NG * DIM * sizeof(float),
                   hipMemcpyDeviceToDevice, stream);
}

// Round 8
// 465.296 us; speedup vs baseline: 1.0449x; 1.0449x over previous
//
#include <hip/hip_runtime.h>

// Graphormer encoder — bf16 MFMA GEMMs, fp32 residual path.
// Attention is block-diagonal (64 graphs x 32 nodes) — never materialize [N,N].
// Round 8: R6 base + XCD-aware swizzled 1-D grids for all GEMMs (same-XCD blocks
// share a row-panel group -> A/B tiles reuse in per-XCD L2) + merged prep kernels.

#define NG   64
#define NP   31
#define NORI 1984
#define NT   2048
#define DIM  512
#define NHD  8
#define DKH  64
#define FFD  2048
#define NLAY 4
#define NFEA 32

typedef __attribute__((ext_vector_type(8))) short short8;
typedef __attribute__((ext_vector_type(4))) float floatx4;

__device__ __forceinline__ unsigned short f2bf(float f) {
    union { float f; unsigned u; } v; v.f = f;
    unsigned r = v.u + 0x7fffu + ((v.u >> 16) & 1u);
    return (unsigned short)(r >> 16);
}
__device__ __forceinline__ float bf2f(unsigned short u) {
    union { unsigned u; float f; } v; v.u = ((unsigned)u) << 16;
    return v.f;
}

// ---------------------------------------------------------------- init h + build B (merged)
__global__ __launch_bounds__(256) void init_h(
    const float* __restrict__ x, const int* __restrict__ degrees,
    const float* __restrict__ init_W, const float* __restrict__ init_b,
    const float* __restrict__ cent_emb, float* __restrict__ h,
    const int* __restrict__ sp, const float* __restrict__ db,
    const float* __restrict__ virt_bias, float* __restrict__ Bg)
{
    int n = blockIdx.x;
    int tid = threadIdx.x;
    if (n >= NT) {               // build_B part: one block per graph
        int g = n - NT;
        float vb = virt_bias[0];
        for (int e = tid; e < 1024; e += 256) {
            int i = e >> 5, j = e & 31;
            float v;
            if (i == j) v = db[0];
            else if (i < NP && j < NP) {
                int s = sp[(size_t)(g * NP + i) * NORI + g * NP + j];
                v = db[s < 100 ? s : 100];
            } else v = vb;
            Bg[(size_t)g * 1024 + e] = v;
        }
        return;
    }
    __shared__ float xs[NFEA];
    if (n < NORI && tid < NFEA) xs[tid] = x[(size_t)n * NFEA + tid];
    __syncthreads();
    int deg = degrees[n]; if (deg > 100) deg = 100;
    for (int d = tid; d < DIM; d += 256) {
        float v = cent_emb[(size_t)deg * DIM + d];
        if (n < NORI) {
            float acc = init_b[d];
            #pragma unroll
            for (int k = 0; k < NFEA; ++k) acc += xs[k] * init_W[(size_t)k * DIM + d];
            v += acc;
        }
        h[(size_t)n * DIM + d] = v;
    }
}

// ---------------------------------------------------------------- weight prep (QKV + bias merged)
// Wq/Wk/Wv [L,H,D,DK] -> Wqkv_t [L][1536][512] bf16 (row = which*512+h*64+k, col = d)
__global__ __launch_bounds__(256) void qkv_prep(
    const float* __restrict__ Wq, const float* __restrict__ Wk, const float* __restrict__ Wv,
    const float* __restrict__ bq, const float* __restrict__ bk, const float* __restrict__ bv,
    unsigned short* __restrict__ Wt, float* __restrict__ bqkv)
{
    int tile = blockIdx.x;
    if (tile >= 3072) {          // bias part: 24 blocks cover NLAY*1536
        int idx = (tile - 3072) * 256 + threadIdx.x;
        if (idx < NLAY * 1536) {
            int l = idx / 1536, c = idx % 1536;
            int which = c >> 9, cc = c & 511;
            const float* b = (which == 0) ? bq : (which == 1) ? bk : bv;
            bqkv[idx] = b[(size_t)l * 512 + cc];
        }
        return;
    }
    int slice = tile >> 5;
    int tloc = tile & 31;
    int dt = tloc >> 1, kt = tloc & 1;
    int l = slice / 24; int rem = slice % 24; int which = rem >> 3; int hh = rem & 7;
    const float* W = (which == 0) ? Wq : (which == 1) ? Wk : Wv;
    const float* in = W + (size_t)(l * 8 + hh) * DIM * DKH;
    __shared__ float tl[32][33];
    int tr = threadIdx.x >> 5, tc = threadIdx.x & 31;
    #pragma unroll
    for (int p = 0; p < 4; ++p)
        tl[tr + p * 8][tc] = in[(size_t)(dt * 32 + tr + p * 8) * DKH + kt * 32 + tc];
    __syncthreads();
    unsigned short* out = Wt + ((size_t)l * 1536 + which * 512 + hh * 64 + kt * 32) * DIM + dt * 32;
    #pragma unroll
    for (int p = 0; p < 4; ++p)
        out[(size_t)(tr + p * 8) * DIM + tc] = f2bf(tl[tc][tr + p * 8]);
}

// combined transpose of Wo/W1/W2 -> [C][R] bf16, one launch.
__global__ __launch_bounds__(256) void prep_w(
    const float* __restrict__ Wo, const float* __restrict__ W1, const float* __restrict__ W2,
    unsigned short* __restrict__ Wo_t, unsigned short* __restrict__ W1_t,
    unsigned short* __restrict__ W2_t)
{
    int id = blockIdx.x;
    const float* in; unsigned short* out; int R, C, l, rt, ct;
    if (id < 1024) {
        l = id >> 8; int t = id & 255; rt = t >> 4; ct = t & 15;
        in = Wo; out = Wo_t; R = 512; C = 512;
    } else if (id < 5120) {
        int t2 = id - 1024; l = t2 >> 10; int t = t2 & 1023; rt = t >> 6; ct = t & 63;
        in = W1; out = W1_t; R = 512; C = 2048;
    } else {
        int t2 = id - 5120; l = t2 >> 10; int t = t2 & 1023; rt = t >> 4; ct = t & 15;
        in = W2; out = W2_t; R = 2048; C = 512;
    }
    const float* ip = in + (size_t)l * R * C;
    unsigned short* op = out + (size_t)l * R * C;
    int r0 = rt * 32, c0 = ct * 32;
    __shared__ float tl[32][33];
    int tr = threadIdx.x >> 5, tc = threadIdx.x & 31;
    #pragma unroll
    for (int p = 0; p < 4; ++p)
        tl[tr + p * 8][tc] = ip[(size_t)(r0 + tr + p * 8) * C + c0 + tc];
    __syncthreads();
    #pragma unroll
    for (int p = 0; p < 4; ++p)
        op[(size_t)(c0 + tr + p * 8) * R + r0 + tc] = f2bf(tl[tc][tr + p * 8]);
}

// ---------------------------------------------------------------- layernorm: fp32 in -> bf16 out
__global__ __launch_bounds__(256) void layernorm_bf16(
    const float* __restrict__ in, unsigned short* __restrict__ out, int row0)
{
    int n = row0 + blockIdx.x;
    int tid = threadIdx.x;
    const float* row = in + (size_t)n * DIM;
    float v0 = row[tid], v1 = row[tid + 256];
    float s = v0 + v1;
    float sq = v0 * v0 + v1 * v1;
    #pragma unroll
    for (int off = 32; off > 0; off >>= 1) {
        s  += __shfl_down(s, off);
        sq += __shfl_down(sq, off);
    }
    __shared__ float red[8];
    int wave = tid >> 6;
    if ((tid & 63) == 0) { red[wave] = s; red[4 + wave] = sq; }
    __syncthreads();
    float ts  = red[0] + red[1] + red[2] + red[3];
    float tsq = red[4] + red[5] + red[6] + red[7];
    float m   = ts * (1.0f / DIM);
    float var = tsq * (1.0f / DIM) - m * m;
    float inv = rsqrtf(var + 1e-5f);
    out[(size_t)n * DIM + tid]       = f2bf((v0 - m) * inv);
    out[(size_t)n * DIM + tid + 256] = f2bf((v1 - m) * inv);
}

// ---------------------------------------------------------------- bf16 MFMA GEMM, XCD-swizzled
// C = A@Bt^T. Tile 64x64x64, 256 thr, wave = 32x32 (2x2 frags). 1-D grid P*C*SPLITK.
// Decode (P>=8): xcd = id&7 owns row-panels {xcd, xcd+8, ...}; cols sweep fastest,
// then split-K slice -> per-XCD L2 keeps A row-panels + B col-panels resident.
// SPLITK==1: out = +bias (+relu), fp32/bf16 per flags.
// SPLITK>1:  atomicAdd partials into fp32 out (already holds residual); z==0 adds bias.
// flags: 1 = relu, 2 = bf16 output, 4 = last-QKV (skip Q cols for non-virt rows)
template<int SPLITK>
__global__ __launch_bounds__(256) void gemm64(
    const unsigned short* __restrict__ A, const unsigned short* __restrict__ Bt,
    const float* __restrict__ bias, void* __restrict__ out,
    int Nfull, int K, int moff, int flags, int P, int C)
{
    __shared__ __align__(16) unsigned short Asl[64 * 72];
    __shared__ __align__(16) unsigned short Bsl[64 * 72];
    int id = blockIdx.x;
    int by, bx, bz;
    if (P >= 8) {
        int xcd = id & 7, t = id >> 3, G = P >> 3;
        by = xcd + 8 * (t % G);
        int r2 = t / G;
        bx = r2 % C;
        bz = r2 / C;
    } else {
        by = id % P; int r2 = id / P; bx = r2 % C; bz = r2 / C;
    }
    int tid = threadIdx.x;
    int row0 = moff + by * 64, col0 = bx * 64;
    if ((flags & 4) && col0 < 512 && row0 < NORI) return;   // last layer: Q only for virt rows
    int kslice = K / SPLITK;
    int kbeg = bz * kslice;
    int wave = tid >> 6, lane = tid & 63;
    int quad = lane >> 4, m16 = lane & 15;
    int mw = (wave >> 1) * 32, nw = (wave & 1) * 32;
    floatx4 acc[2][2] = {};
    for (int k0 = kbeg; k0 < kbeg + kslice; k0 += 64) {
        #pragma unroll
        for (int p = 0; p < 2; ++p) {
            int idx = (p * 256 + tid) * 8;
            int r = idx >> 6, kk = idx & 63;
            *(float4*)(Asl + r * 72 + kk) =
                *(const float4*)(A + (size_t)(row0 + r) * K + k0 + kk);
            *(float4*)(Bsl + r * 72 + kk) =
                *(const float4*)(Bt + (size_t)(col0 + r) * K + k0 + kk);
        }
        __syncthreads();
        #pragma unroll
        for (int ks = 0; ks < 64; ks += 32) {
            short8 a[2], b[2];
            #pragma unroll
            for (int mi = 0; mi < 2; ++mi)
                a[mi] = *(const short8*)(Asl + (mw + mi * 16 + m16) * 72 + ks + quad * 8);
            #pragma unroll
            for (int ni = 0; ni < 2; ++ni)
                b[ni] = *(const short8*)(Bsl + (nw + ni * 16 + m16) * 72 + ks + quad * 8);
            #pragma unroll
            for (int mi = 0; mi < 2; ++mi)
                #pragma unroll
                for (int ni = 0; ni < 2; ++ni)
                    acc[mi][ni] = __builtin_amdgcn_mfma_f32_16x16x32_bf16(
                        a[mi], b[ni], acc[mi][ni], 0, 0, 0);
        }
        __syncthreads();
    }
    if (SPLITK == 1) {
        int do_relu = flags & 1, out_bf = flags & 2;
        #pragma unroll
        for (int mi = 0; mi < 2; ++mi) {
            #pragma unroll
            for (int ni = 0; ni < 2; ++ni) {
                int col = col0 + nw + ni * 16 + m16;
                float bval = bias[col];
                #pragma unroll
                for (int rr = 0; rr < 4; ++rr) {
                    int row = row0 + mw + mi * 16 + quad * 4 + rr;
                    float v = acc[mi][ni][rr] + bval;
                    if (do_relu) v = fmaxf(v, 0.0f);
                    if (out_bf) ((unsigned short*)out)[(size_t)row * Nfull + col] = f2bf(v);
                    else        ((float*)out)[(size_t)row * Nfull + col] = v;
                }
            }
        }
    } else {
        float* o = (float*)out;
        float bscale = (bz == 0) ? 1.0f : 0.0f;
        #pragma unroll
        for (int mi = 0; mi < 2; ++mi) {
            #pragma unroll
            for (int ni = 0; ni < 2; ++ni) {
                int col = col0 + nw + ni * 16 + m16;
                float bval = bias[col] * bscale;
                #pragma unroll
                for (int rr = 0; rr < 4; ++rr) {
                    int row = row0 + mw + mi * 16 + quad * 4 + rr;
                    atomicAdd(&o[(size_t)row * Nfull + col], acc[mi][ni][rr] + bval);
                }
            }
        }
    }
}

// ---------------------------------------------------------------- block attention (layers 0..2)
__global__ __launch_bounds__(256) void attention(
    const unsigned short* __restrict__ qkv,  // [NT][1536] bf16, Q|K|V head-major
    const float* __restrict__ Bg,            // [NG][32][32]
    unsigned short* __restrict__ O)          // [NT][512] bf16 head-major
{
    int g = blockIdx.x >> 3;
    int hh = blockIdx.x & 7;
    __shared__ float Qs[32][65], Ks[32][65], Vs[32][65];
    __shared__ float S[32][33];
    int tid = threadIdx.x;
    int i = tid >> 3;
    int c0 = (tid & 7) * 8;
    int gn = (i < NP) ? g * NP + i : NORI + g;
    const unsigned short* base = qkv + (size_t)gn * 1536 + hh * DKH;
    short8 qv = *(const short8*)(base + c0);
    short8 kv = *(const short8*)(base + 512 + c0);
    short8 vv = *(const short8*)(base + 1024 + c0);
    #pragma unroll
    for (int j = 0; j < 8; ++j) {
        Qs[i][c0 + j] = bf2f((unsigned short)qv[j]);
        Ks[i][c0 + j] = bf2f((unsigned short)kv[j]);
        Vs[i][c0 + j] = bf2f((unsigned short)vv[j]);
    }
    __syncthreads();
    const float scale = 0.125f;
    #pragma unroll
    for (int e = 0; e < 4; ++e) {
        int idx = tid + e * 256;
        int si = idx >> 5, sj = idx & 31;
        float dot = 0.0f;
        #pragma unroll
        for (int k = 0; k < DKH; ++k) dot += Qs[si][k] * Ks[sj][k];
        S[si][sj] = dot * scale + Bg[(size_t)g * 1024 + si * 32 + sj];
    }
    __syncthreads();
    if (tid < 32) {
        float mx = -1e30f;
        #pragma unroll
        for (int j = 0; j < 32; ++j) mx = fmaxf(mx, S[tid][j]);
        float sum = 0.0f;
        #pragma unroll
        for (int j = 0; j < 32; ++j) { float e = __expf(S[tid][j] - mx); S[tid][j] = e; sum += e; }
        float inv = 1.0f / sum;
        #pragma unroll
        for (int j = 0; j < 32; ++j) S[tid][j] *= inv;
    }
    __syncthreads();
    short8 ov;
    #pragma unroll
    for (int cc = 0; cc < 8; ++cc) {
        float acc = 0.0f;
        #pragma unroll
        for (int j = 0; j < 32; ++j) acc += S[i][j] * Vs[j][c0 + cc];
        ov[cc] = (short)f2bf(acc);
    }
    *(short8*)(O + (size_t)gn * DIM + hh * DKH + c0) = ov;
}

// ---------------------------------------------------------------- last-layer attention
__global__ __launch_bounds__(64) void attention_last(
    const unsigned short* __restrict__ qkv, const float* __restrict__ Bg,
    unsigned short* __restrict__ O)
{
    int g = blockIdx.x >> 3, hh = blockIdx.x & 7;
    __shared__ float Ks[32][65], Vs[32][65];
    __shared__ float Qs[64], P[32];
    int tid = threadIdx.x;
    int j = tid & 31, hf = tid >> 5;
    int gn = (j < NP) ? g * NP + j : NORI + g;
    const unsigned short* kb = qkv + (size_t)gn * 1536 + hh * DKH + 512 + hf * 32;
    #pragma unroll
    for (int c = 0; c < 32; c += 8) {
        short8 k8 = *(const short8*)(kb + c);
        short8 v8 = *(const short8*)(kb + 512 + c);
        #pragma unroll
        for (int t = 0; t < 8; ++t) {
            Ks[j][hf * 32 + c + t] = bf2f((unsigned short)k8[t]);
            Vs[j][hf * 32 + c + t] = bf2f((unsigned short)v8[t]);
        }
    }
    Qs[tid] = bf2f(qkv[(size_t)(NORI + g) * 1536 + hh * DKH + tid]);
    __syncthreads();
    float s;
    if (tid < 32) {
        float dot = 0.0f;
        #pragma unroll
        for (int k = 0; k < 64; ++k) dot += Qs[k] * Ks[tid][k];
        s = dot * 0.125f + Bg[(size_t)g * 1024 + 31 * 32 + tid];
    } else s = -1e30f;
    float mx = s;
    #pragma unroll
    for (int off = 32; off > 0; off >>= 1) mx = fmaxf(mx, __shfl_xor(mx, off));
    float e = (tid < 32) ? __expf(s - mx) : 0.0f;
    float sum = e;
    #pragma unroll
    for (int off = 32; off > 0; off >>= 1) sum += __shfl_xor(sum, off);
    if (tid < 32) P[tid] = e / sum;
    __syncthreads();
    float acc = 0.0f;
    #pragma unroll
    for (int jj = 0; jj < 32; ++jj) acc += P[jj] * Vs[jj][tid];
    O[(size_t)(NORI + g) * DIM + hh * DKH + tid] = f2bf(acc);
}

// ---------------------------------------------------------------- launch
extern "C" void kernel_launch(void* const* d_in, const int* in_sizes, int n_in,
                              void* d_out, int out_size, void* d_ws, size_t ws_size,
                              hipStream_t stream)
{
    const float* x        = (const float*)d_in[0];
    const int*   sp       = (const int*)d_in[1];
    const int*   degrees  = (const int*)d_in[3];
    const float* init_W   = (const float*)d_in[4];
    const float* init_b   = (const float*)d_in[5];
    const float* cent_emb = (const float*)d_in[6];
    const float* db       = (const float*)d_in[7];
    const float* vbias    = (const float*)d_in[8];
    const float* Wq       = (const float*)d_in[9];
    const float* bq       = (const float*)d_in[10];
    const float* Wk       = (const float*)d_in[11];
    const float* bk       = (const float*)d_in[12];
    const float* Wv       = (const float*)d_in[13];
    const float* bv       = (const float*)d_in[14];
    const float* Wo       = (const float*)d_in[15];
    const float* bo       = (const float*)d_in[16];
    const float* W1       = (const float*)d_in[17];
    const float* b1       = (const float*)d_in[18];
    const float* W2       = (const float*)d_in[19];
    const float* b2       = (const float*)d_in[20];

    char* ws = (char*)d_ws;
    float*          h      = (float*)ws;          ws += (size_t)NT * DIM * 4;
    unsigned short* hn     = (unsigned short*)ws; ws += (size_t)NT * DIM * 2;
    unsigned short* o      = (unsigned short*)ws; ws += (size_t)NT * DIM * 2;
    unsigned short* qkv    = (unsigned short*)ws; ws += (size_t)NT * FFD * 2;      // aliased qkv/ffn
    float*          Bg     = (float*)ws;          ws += (size_t)NG * 1024 * 4;
    unsigned short* Wqkv_t = (unsigned short*)ws; ws += (size_t)NLAY * 1536 * DIM * 2;
    unsigned short* Wo_t   = (unsigned short*)ws; ws += (size_t)NLAY * DIM * DIM * 2;
    unsigned short* W1_t   = (unsigned short*)ws; ws += (size_t)NLAY * FFD * DIM * 2;
    unsigned short* W2_t   = (unsigned short*)ws; ws += (size_t)NLAY * DIM * FFD * 2;
    float*          bqkv   = (float*)ws;          ws += (size_t)NLAY * 1536 * 4;
    unsigned short* ffnb   = qkv;

    // prep (3 launches)
    init_h<<<NT + NG, 256, 0, stream>>>(x, degrees, init_W, init_b, cent_emb, h,
                                        sp, db, vbias, Bg);
    qkv_prep<<<3072 + 24, 256, 0, stream>>>(Wq, Wk, Wv, bq, bk, bv, Wqkv_t, bqkv);
    prep_w<<<9216, 256, 0, stream>>>(Wo, W1, W2, Wo_t, W1_t, W2_t);

    for (int l = 0; l < NLAY - 1; ++l) {
        layernorm_bf16<<<NT, 256, 0, stream>>>(h, hn, 0);
        gemm64<1><<<32 * 24, 256, 0, stream>>>(
            hn, Wqkv_t + (size_t)l * 1536 * DIM, bqkv + (size_t)l * 1536,
            qkv, 1536, DIM, 0, /*bf16 out*/2, 32, 24);
        attention<<<NG * NHD, 256, 0, stream>>>(qkv, Bg, o);
        gemm64<2><<<32 * 8 * 2, 256, 0, stream>>>(
            o, Wo_t + (size_t)l * DIM * DIM, bo + (size_t)l * DIM,
            h, DIM, DIM, 0, 0, 32, 8);
        layernorm_bf16<<<NT, 256, 0, stream>>>(h, hn, 0);
        gemm64<1><<<32 * 32, 256, 0, stream>>>(
            hn, W1_t + (size_t)l * FFD * DIM, b1 + (size_t)l * FFD,
            ffnb, FFD, DIM, 0, /*relu+bf16*/3, 32, 32);
        gemm64<4><<<32 * 8 * 4, 256, 0, stream>>>(
            ffnb, W2_t + (size_t)l * DIM * FFD, b2 + (size_t)l * DIM,
            h, DIM, FFD, 0, 0, 32, 8);
    }

    // ---- last layer: only virtual rows reach the output ----
    {
        int l = NLAY - 1;
        layernorm_bf16<<<NT, 256, 0, stream>>>(h, hn, 0);
        // K,V for all rows; Q only for the virtual row-block (flag 4 early-exits Q x non-virt)
        gemm64<1><<<32 * 24, 256, 0, stream>>>(
            hn, Wqkv_t + (size_t)l * 1536 * DIM, bqkv + (size_t)l * 1536,
            qkv, 1536, DIM, 0, /*bf16 out + lastQKV*/6, 32, 24);
        attention_last<<<NG * NHD, 64, 0, stream>>>(qkv, Bg, o);
        gemm64<8><<<1 * 8 * 8, 256, 0, stream>>>(
            o, Wo_t + (size_t)l * DIM * DIM, bo + (size_t)l * DIM,
            h, DIM, DIM, NORI, 0, 1, 8);
        layernorm_bf16<<<NG, 256, 0, stream>>>(h, hn, NORI);
        gemm64<1><<<1 * 32, 256, 0, stream>>>(
            hn, W1_t + (size_t)l * FFD * DIM, b1 + (size_t)l * FFD,
            ffnb, FFD, DIM, NORI, 3, 1, 32);
        gemm64<8><<<1 * 8 * 8, 256, 0, stream>>>(
            ffnb, W2_t + (size_t)l * DIM * FFD, b2 + (size_t)l * DIM,
            h, DIM, FFD, NORI, 0, 1, 8);
    }

    hipMemcpyAsync(d_out, h + (size_t)NORI * DIM, (size_t)NG * DIM * sizeof(float),
                   hipMemcpyDeviceToDevice, stream);
}